// Round 1
// baseline (6339.326 us; speedup 1.0000x reference)
//
#include <hip/hip_runtime.h>
#include <math.h>

// ---------------- CSR construction ----------------

static __global__ void k_count(const int* __restrict__ col, int* __restrict__ cnt, int E) {
  int e = blockIdx.x * blockDim.x + threadIdx.x;
  if (e < E) atomicAdd(&cnt[col[e]], 1);
}

static __global__ void k_dinv(const int* __restrict__ cnt, float* __restrict__ dinv, int N) {
  int v = blockIdx.x * blockDim.x + threadIdx.x;
  if (v < N) dinv[v] = rsqrtf((float)cnt[v] + 1.0f);  // +1 = self-loop
}

// exclusive prefix sum of cnt -> rowptr[0..N], single block of 1024
static __global__ void k_scan(const int* __restrict__ cnt, int* __restrict__ rowptr, int N) {
  __shared__ int buf[1024];
  __shared__ int carry;
  int t = threadIdx.x;
  if (t == 0) carry = 0;
  __syncthreads();
  for (int base = 0; base < N; base += 1024) {
    int i = base + t;
    int x = (i < N) ? cnt[i] : 0;
    buf[t] = x;
    __syncthreads();
    for (int o = 1; o < 1024; o <<= 1) {
      int val = (t >= o) ? buf[t - o] : 0;
      __syncthreads();
      buf[t] += val;
      __syncthreads();
    }
    int inc = buf[t];                 // inclusive within chunk
    if (i < N) rowptr[i] = carry + inc - x;  // exclusive
    __syncthreads();
    if (t == 1023) carry += inc;      // chunk total
    __syncthreads();
  }
  if (t == 0) rowptr[N] = carry;
}

static __global__ void k_fill(const int* __restrict__ row, const int* __restrict__ col,
                              const float* __restrict__ dinv, const int* __restrict__ rowptr,
                              int* __restrict__ fillc, int* __restrict__ csr_src,
                              float* __restrict__ csr_w, int E) {
  int e = blockIdx.x * blockDim.x + threadIdx.x;
  if (e >= E) return;
  int s = row[e], d = col[e];
  int pos = rowptr[d] + atomicAdd(&fillc[d], 1);
  csr_src[pos] = s;
  csr_w[pos] = dinv[s] * dinv[d];
}

// ---------------- GEMM: Y[M,Nc] = (relu?)X[M,K] @ W[K,Nc] ----------------

#define BM 64
#define BN 64
#define BKK 16

static __global__ __launch_bounds__(256) void k_gemm(
    const float* __restrict__ X, const float* __restrict__ W, float* __restrict__ Y,
    int M, int K, int Nc, int doRelu) {
  __shared__ float As[BKK][BM + 4];   // [k][m]
  __shared__ float Bs[BKK][BN + 4];   // [k][n]
  int bm = blockIdx.x * BM;
  int bn = blockIdx.y * BN;
  int tid = threadIdx.x;
  int tx = tid & 15;   // n
  int ty = tid >> 4;   // m
  float acc[4][4];
#pragma unroll
  for (int i = 0; i < 4; ++i)
#pragma unroll
    for (int j = 0; j < 4; ++j) acc[i][j] = 0.f;

  for (int k0 = 0; k0 < K; k0 += BKK) {
    for (int l = tid; l < BM * BKK; l += 256) {
      int m = l >> 4, kk = l & 15;
      int gm = bm + m, gk = k0 + kk;
      float v = 0.f;
      if (gm < M && gk < K) v = X[(size_t)gm * K + gk];
      if (doRelu) v = fmaxf(v, 0.f);
      As[kk][m] = v;
    }
    for (int l = tid; l < BKK * BN; l += 256) {
      int kk = l >> 6, n = l & 63;
      int gk = k0 + kk, gn = bn + n;
      float v = 0.f;
      if (gk < K && gn < Nc) v = W[(size_t)gk * Nc + gn];
      Bs[kk][n] = v;
    }
    __syncthreads();
#pragma unroll
    for (int kk = 0; kk < BKK; ++kk) {
      float a[4], b[4];
#pragma unroll
      for (int i = 0; i < 4; ++i) a[i] = As[kk][ty * 4 + i];
#pragma unroll
      for (int j = 0; j < 4; ++j) b[j] = Bs[kk][tx * 4 + j];
#pragma unroll
      for (int i = 0; i < 4; ++i)
#pragma unroll
        for (int j = 0; j < 4; ++j) acc[i][j] += a[i] * b[j];
    }
    __syncthreads();
  }
#pragma unroll
  for (int i = 0; i < 4; ++i) {
    int gm = bm + ty * 4 + i;
    if (gm >= M) continue;
#pragma unroll
    for (int j = 0; j < 4; ++j) {
      int gn = bn + tx * 4 + j;
      if (gn < Nc) Y[(size_t)gm * Nc + gn] = acc[i][j];
    }
  }
}

// ---------------- aggregation: Y[v,c] = b[c] + dinv[v]^2*H[v,c] + sum_e w_e*H[src_e,c] ----

static __global__ void k_aggregate(const float* __restrict__ Hm, float* __restrict__ Y,
                                   const int* __restrict__ rowptr, const int* __restrict__ csr_src,
                                   const float* __restrict__ csr_w, const float* __restrict__ dinv,
                                   const float* __restrict__ bias, int N, int C) {
  int idx = blockIdx.x * blockDim.x + threadIdx.x;
  int total = N * C;
  if (idx >= total) return;
  int v = idx / C, c = idx - v * C;
  float dv = dinv[v];
  float acc = dv * dv * Hm[(size_t)v * C + c];
  int s = rowptr[v], e = rowptr[v + 1];
  for (int i = s; i < e; ++i) {
    acc += csr_w[i] * Hm[(size_t)csr_src[i] * C + c];
  }
  Y[idx] = acc + bias[c];
}

// ---------------- instance norm ----------------

static __global__ void k_instnorm_stats(const float* __restrict__ X, float* __restrict__ meanv,
                                        float* __restrict__ scalev, int N, int C) {
  int c = blockIdx.x;      // one block per channel
  int t = threadIdx.x;     // 256
  float s = 0.f, s2 = 0.f;
  for (int v = t; v < N; v += 256) {
    float x = X[(size_t)v * C + c];
    s += x;
    s2 += x * x;
  }
  __shared__ float ls[256], ls2[256];
  ls[t] = s; ls2[t] = s2;
  __syncthreads();
  for (int o = 128; o > 0; o >>= 1) {
    if (t < o) { ls[t] += ls[t + o]; ls2[t] += ls2[t + o]; }
    __syncthreads();
  }
  if (t == 0) {
    float m = ls[0] / (float)N;
    float var = ls2[0] / (float)N - m * m;
    meanv[c] = m;
    scalev[c] = rsqrtf(var + 1e-5f);
  }
}

static __global__ void k_instnorm_apply(float* __restrict__ X, const float* __restrict__ meanv,
                                        const float* __restrict__ scalev, int N, int C) {
  int idx = blockIdx.x * blockDim.x + threadIdx.x;
  if (idx >= N * C) return;
  int c = idx % C;
  X[idx] = (X[idx] - meanv[c]) * scalev[c];
}

// ---------------- elementwise ----------------

static __global__ void k_tanh(float* __restrict__ X, int n) {
  int i = blockIdx.x * blockDim.x + threadIdx.x;
  if (i < n) X[i] = tanhf(X[i]);
}

static __global__ void k_copy(const float* __restrict__ A, float* __restrict__ B, int n) {
  int i = blockIdx.x * blockDim.x + threadIdx.x;
  if (i < n) B[i] = A[i];
}

static __global__ void k_concat(const float* __restrict__ F, const float* __restrict__ Msh,
                                float* __restrict__ X, int N, int NF, int H) {
  int idx = blockIdx.x * blockDim.x + threadIdx.x;
  int DIN = NF + H;
  if (idx >= N * DIN) return;
  int v = idx / DIN, c = idx - v * DIN;
  X[idx] = (c < NF) ? F[v * NF + c] : Msh[(size_t)v * H + (c - NF)];
}

static __global__ void k_step_finish(const float* __restrict__ fdot_pre,
                                     const float* __restrict__ Fcur, float* __restrict__ Fnext,
                                     float* __restrict__ out, int N, int NF, int T, int t) {
  int idx = blockIdx.x * blockDim.x + threadIdx.x;
  if (idx >= N * NF) return;
  int v = idx / NF, f = idx - v * NF;
  float fd = tanhf(fdot_pre[idx]);
  float fn = tanhf(Fcur[idx] + fd * 0.1f);   // DT = 5*(4/200) = 0.1
  Fnext[idx] = fn;
  out[((size_t)v * T + t) * NF + f] = fn;                       // Fs
  out[(size_t)N * T * NF + ((size_t)v * T + t) * NF + f] = fd;  // F_dots
}

// ---------------- host orchestration ----------------

extern "C" void kernel_launch(void* const* d_in, const int* in_sizes, int n_in,
                              void* d_out, int out_size, void* d_ws, size_t ws_size,
                              hipStream_t stream) {
  const float* F0        = (const float*)d_in[0];
  const int*   ei        = (const int*)d_in[1];
  const float* meshfield = (const float*)d_in[2];
  const float* mesh_W0 = (const float*)d_in[4];
  const float* mesh_b0 = (const float*)d_in[5];
  const float* mesh_Wh = (const float*)d_in[6];
  const float* mesh_bh = (const float*)d_in[7];
  const float* mesh_W9 = (const float*)d_in[8];
  const float* mesh_b9 = (const float*)d_in[9];
  const float* diff_W0 = (const float*)d_in[10];
  const float* diff_b0 = (const float*)d_in[11];
  const float* diff_Wh = (const float*)d_in[12];
  const float* diff_bh = (const float*)d_in[13];
  const float* diff_W9 = (const float*)d_in[14];
  const float* diff_b9 = (const float*)d_in[15];

  const int NF = 4;
  const int N  = in_sizes[0] / NF;        // 30000
  const int E  = in_sizes[1] / 2;         // 480000
  const int NM = in_sizes[2] / N;         // 8
  const int H  = in_sizes[5];             // 128
  const int T  = out_size / (N * NF * 2); // 4
  const int DIN = NF + H;                 // 132
  const int DEPTH = in_sizes[7] / H;      // 8 mid convs

  const int* erow = ei;
  const int* ecol = ei + E;

  // workspace carve
  char* p = (char*)d_ws;
  auto alloc = [&](size_t bytes) { char* r = p; p += (bytes + 255) & ~(size_t)255; return r; };
  float* dinv    = (float*)alloc((size_t)N * 4);
  float* bufA    = (float*)alloc((size_t)N * DIN * 4);   // conv input / 132-wide concat
  float* bufB    = (float*)alloc((size_t)N * H * 4);     // gemm output
  float* meshL   = (float*)alloc((size_t)N * H * 4);     // mesh latent (persistent)
  float* fdot    = (float*)alloc((size_t)N * NF * 4);
  float* fcur0   = (float*)alloc((size_t)N * NF * 4);
  float* fcur1   = (float*)alloc((size_t)N * NF * 4);
  float* meanv   = (float*)alloc((size_t)H * 4);
  float* scalev  = (float*)alloc((size_t)H * 4);
  float* csr_w   = (float*)alloc((size_t)E * 4);
  int*   cnt     = (int*)alloc((size_t)N * 4);
  int*   rowptr  = (int*)alloc((size_t)(N + 1) * 4);
  int*   fillc   = (int*)alloc((size_t)N * 4);
  int*   csr_src = (int*)alloc((size_t)E * 4);

  // ---- graph normalization + CSR (by destination) ----
  hipMemsetAsync(cnt, 0, (size_t)N * 4, stream);
  hipMemsetAsync(fillc, 0, (size_t)N * 4, stream);
  k_count<<<(E + 255) / 256, 256, 0, stream>>>(ecol, cnt, E);
  k_dinv<<<(N + 255) / 256, 256, 0, stream>>>(cnt, dinv, N);
  k_scan<<<1, 1024, 0, stream>>>(cnt, rowptr, N);
  k_fill<<<(E + 255) / 256, 256, 0, stream>>>(erow, ecol, dinv, rowptr, fillc, csr_src, csr_w, E);

  auto gemm = [&](const float* X, const float* W, float* Y, int M, int K, int Nc, int relu) {
    dim3 g((M + BM - 1) / BM, (Nc + BN - 1) / BN);
    k_gemm<<<g, 256, 0, stream>>>(X, W, Y, M, K, Nc, relu);
  };
  auto aggregate = [&](const float* Hm, float* Y, const float* bias, int C) {
    int total = N * C;
    k_aggregate<<<(total + 255) / 256, 256, 0, stream>>>(Hm, Y, rowptr, csr_src, csr_w, dinv, bias, N, C);
  };
  auto instnorm = [&](float* X) {
    k_instnorm_stats<<<H, 256, 0, stream>>>(X, meanv, scalev, N, H);
    int total = N * H;
    k_instnorm_apply<<<(total + 255) / 256, 256, 0, stream>>>(X, meanv, scalev, N, H);
  };

  // ---- mesh descriptor block ----
  gemm(meshfield, mesh_W0, bufB, N, NM, H, 0);
  aggregate(bufB, bufA, mesh_b0, H);
  instnorm(bufA);
  for (int i = 0; i < DEPTH; ++i) {
    gemm(bufA, mesh_Wh + (size_t)i * H * H, bufB, N, H, H, 1);
    aggregate(bufB, bufA, mesh_bh + (size_t)i * H, H);
  }
  gemm(bufA, mesh_W9, bufB, N, H, H, 0);
  aggregate(bufB, meshL, mesh_b9, H);
  k_tanh<<<(N * H + 255) / 256, 256, 0, stream>>>(meshL, N * H);

  // ---- recurrent differentiator ----
  k_copy<<<(N * NF + 255) / 256, 256, 0, stream>>>(F0, fcur0, N * NF);
  float* fc = fcur0;
  float* fn = fcur1;
  float* out = (float*)d_out;

  for (int t = 0; t < T; ++t) {
    k_concat<<<(N * DIN + 255) / 256, 256, 0, stream>>>(fc, meshL, bufA, N, NF, H);
    gemm(bufA, diff_W0, bufB, N, DIN, H, 0);
    aggregate(bufB, bufA, diff_b0, H);
    instnorm(bufA);
    for (int i = 0; i < DEPTH; ++i) {
      gemm(bufA, diff_Wh + (size_t)i * H * H, bufB, N, H, H, 1);
      aggregate(bufB, bufA, diff_bh + (size_t)i * H, H);
    }
    gemm(bufA, diff_W9, bufB, N, H, NF, 0);
    aggregate(bufB, fdot, diff_b9, NF);
    k_step_finish<<<(N * NF + 255) / 256, 256, 0, stream>>>(fdot, fc, fn, out, N, NF, T, t);
    float* tmp = fc; fc = fn; fn = tmp;
  }
}

// Round 3
// 2092.330 us; speedup vs baseline: 3.0298x; 3.0298x over previous
//
#include <hip/hip_runtime.h>
#include <math.h>

typedef __attribute__((ext_vector_type(8))) short short8;
typedef __attribute__((ext_vector_type(4))) float f32x4;
typedef unsigned int uint;
typedef unsigned short ushort;

__device__ __forceinline__ ushort f2bf(float f) {
  union { float f; uint u; } v; v.f = f;
  uint u = v.u;
  uint r = (u + 0x7FFFu + ((u >> 16) & 1u)) >> 16;
  return (ushort)r;
}
__device__ __forceinline__ float bflo(uint u) { union { uint u; float f; } v; v.u = u << 16; return v.f; }
__device__ __forceinline__ float bfhi(uint u) { union { uint u; float f; } v; v.u = u & 0xFFFF0000u; return v.f; }
__device__ __forceinline__ uint packbf(float a, float b) { return (uint)f2bf(a) | ((uint)f2bf(b) << 16); }

// ---------------- CSR construction ----------------

static __global__ void k_count(const int* __restrict__ col, int* __restrict__ cnt, int E) {
  int e = blockIdx.x * blockDim.x + threadIdx.x;
  if (e < E) atomicAdd(&cnt[col[e]], 1);
}

static __global__ void k_dinv(const int* __restrict__ cnt, float* __restrict__ dinv, int N) {
  int v = blockIdx.x * blockDim.x + threadIdx.x;
  if (v < N) dinv[v] = rsqrtf((float)cnt[v] + 1.0f);  // +1 = self-loop
}

static __global__ void k_scan(const int* __restrict__ cnt, int* __restrict__ rowptr, int N) {
  __shared__ int buf[1024];
  __shared__ int carry;
  int t = threadIdx.x;
  if (t == 0) carry = 0;
  __syncthreads();
  for (int base = 0; base < N; base += 1024) {
    int i = base + t;
    int x = (i < N) ? cnt[i] : 0;
    buf[t] = x;
    __syncthreads();
    for (int o = 1; o < 1024; o <<= 1) {
      int val = (t >= o) ? buf[t - o] : 0;
      __syncthreads();
      buf[t] += val;
      __syncthreads();
    }
    int inc = buf[t];
    if (i < N) rowptr[i] = carry + inc - x;
    __syncthreads();
    if (t == 1023) carry += inc;
    __syncthreads();
  }
  if (t == 0) rowptr[N] = carry;
}

static __global__ void k_fill(const int* __restrict__ row, const int* __restrict__ col,
                              const float* __restrict__ dinv, const int* __restrict__ rowptr,
                              int* __restrict__ fillc, int* __restrict__ csr_src,
                              float* __restrict__ csr_w, int E) {
  int e = blockIdx.x * blockDim.x + threadIdx.x;
  if (e >= E) return;
  int s = row[e], d = col[e];
  int pos = rowptr[d] + atomicAdd(&fillc[d], 1);
  csr_src[pos] = s;
  csr_w[pos] = dinv[s] * dinv[d];
}

// ---------------- weight prep: W[K,Nc] fp32 -> Wt[n][kpad] bf16 (n-major, K zero-padded) ----

static __global__ void k_wprep(const float* __restrict__ W, ushort* __restrict__ Wt,
                               int K, int Kpad, int Nc) {
  int l = blockIdx.y;
  int idx = blockIdx.x * 256 + threadIdx.x;
  if (idx >= Nc * Kpad) return;
  int n = idx / Kpad, k = idx - n * Kpad;
  const float* Wl = W + (size_t)l * K * Nc;
  ushort* Wtl = Wt + (size_t)l * Nc * Kpad;
  Wtl[idx] = (k < K) ? f2bf(Wl[(size_t)k * Nc + n]) : (ushort)0;
}

// ---------------- MFMA GEMM: Y[M,128] = A[M,K] @ B[K,128], all bf16, fp32 accum ----------

static __global__ __launch_bounds__(256) void k_gemm16(
    const ushort* __restrict__ A, const ushort* __restrict__ Bt,  // Bt: [128 n][K]
    ushort* __restrict__ Y, int M, int K) {
  __shared__ ushort As[128 * 40];  // rows padded 32->40 ushorts: even LDS bank spread
  __shared__ ushort Bs[128 * 40];
  const int tid = threadIdx.x;
  const int lane = tid & 63;
  const int wave = tid >> 6;
  const int wr = wave >> 1, wc = wave & 1;
  const int bm = blockIdx.x * 128;
  const int l15 = lane & 15, lk = lane >> 4;
  const int r0 = tid >> 2, o0 = tid & 3;  // this thread stages chunks (r0,o0) and (r0+64,o0)

  f32x4 acc[4][4];
#pragma unroll
  for (int i = 0; i < 4; ++i)
#pragma unroll
    for (int j = 0; j < 4; ++j) acc[i][j] = (f32x4){0.f, 0.f, 0.f, 0.f};

  for (int k0 = 0; k0 < K; k0 += 32) {
    short8 a0 = *(const short8*)(A + (size_t)(bm + r0) * K + k0 + o0 * 8);
    short8 a1 = *(const short8*)(A + (size_t)(bm + r0 + 64) * K + k0 + o0 * 8);
    short8 b0 = *(const short8*)(Bt + (size_t)r0 * K + k0 + o0 * 8);
    short8 b1 = *(const short8*)(Bt + (size_t)(r0 + 64) * K + k0 + o0 * 8);
    __syncthreads();  // previous iter's LDS reads complete before overwrite
    *(short8*)(As + r0 * 40 + o0 * 8) = a0;
    *(short8*)(As + (r0 + 64) * 40 + o0 * 8) = a1;
    *(short8*)(Bs + r0 * 40 + o0 * 8) = b0;
    *(short8*)(Bs + (r0 + 64) * 40 + o0 * 8) = b1;
    __syncthreads();
    short8 af[4], bfr[4];
#pragma unroll
    for (int i = 0; i < 4; ++i) {
      af[i]  = *(const short8*)(As + (wr * 64 + i * 16 + l15) * 40 + lk * 8);
      bfr[i] = *(const short8*)(Bs + (wc * 64 + i * 16 + l15) * 40 + lk * 8);
    }
#pragma unroll
    for (int i = 0; i < 4; ++i)
#pragma unroll
      for (int j = 0; j < 4; ++j)
        acc[i][j] = __builtin_amdgcn_mfma_f32_16x16x32_bf16(af[i], bfr[j], acc[i][j], 0, 0, 0);
  }
  // epilogue: C/D layout col = lane&15, row = (lane>>4)*4 + reg
#pragma unroll
  for (int i = 0; i < 4; ++i) {
#pragma unroll
    for (int r = 0; r < 4; ++r) {
      int row = bm + wr * 64 + i * 16 + lk * 4 + r;
      if (row < M) {
#pragma unroll
        for (int j = 0; j < 4; ++j) {
          int col = wc * 64 + j * 16 + l15;
          Y[(size_t)row * 128 + col] = f2bf(acc[i][j][r]);
        }
      }
    }
  }
}

// ---------------- small GEMM: Y[M,4] = A16[M,128] @ W[128,4] fp32 out ----------------

static __global__ __launch_bounds__(256) void k_gemm_small(
    const ushort* __restrict__ A, const float* __restrict__ W, float* __restrict__ Y, int M) {
  __shared__ float Ws[512];
  int tid = threadIdx.x;
  for (int i = tid; i < 512; i += 256) Ws[i] = W[i];
  __syncthreads();
  int m = blockIdx.x * 256 + tid;
  if (m >= M) return;
  const uint* a = (const uint*)(A + (size_t)m * 128);
  float a0 = 0, a1 = 0, a2 = 0, a3 = 0;
#pragma unroll 8
  for (int k2 = 0; k2 < 64; ++k2) {
    uint u = a[k2];
    float x0 = bflo(u), x1 = bfhi(u);
    const float* w = Ws + k2 * 8;
    a0 += x0 * w[0] + x1 * w[4];
    a1 += x0 * w[1] + x1 * w[5];
    a2 += x0 * w[2] + x1 * w[6];
    a3 += x0 * w[3] + x1 * w[7];
  }
  float* y = Y + (size_t)m * 4;
  y[0] = a0; y[1] = a1; y[2] = a2; y[3] = a3;
}

// ---------------- aggregation (C=128, bf16 messages): wave = 1 node, lane = 2 channels ----

static __global__ __launch_bounds__(256) void k_agg16(
    const ushort* __restrict__ Hm, const int* __restrict__ rowptr,
    const int* __restrict__ csr_src, const float* __restrict__ csr_w,
    const float* __restrict__ dinv, const float* __restrict__ bias,
    float* __restrict__ outF, int actF,      // fp32 out (nullable), actF: 0 none, 2 tanh
    ushort* __restrict__ outB, int reluB,    // bf16 out stride 128 (nullable)
    int N) {
  int node = blockIdx.x * 4 + (threadIdx.x >> 6);
  if (node >= N) return;
  int lane = threadIdx.x & 63;
  const uint* __restrict__ Hu = (const uint*)Hm;  // 64 uints per 128-ch row
  float dv = dinv[node];
  float w = dv * dv;
  uint su = Hu[(size_t)node * 64 + lane];
  float acc0 = w * bflo(su), acc1 = w * bfhi(su);
  int s = rowptr[node], e = rowptr[node + 1];
  int i = s;
  for (; i + 4 <= e; i += 4) {
    int s0 = csr_src[i], s1 = csr_src[i + 1], s2 = csr_src[i + 2], s3 = csr_src[i + 3];
    float w0 = csr_w[i], w1 = csr_w[i + 1], w2 = csr_w[i + 2], w3 = csr_w[i + 3];
    uint u0 = Hu[(size_t)s0 * 64 + lane];
    uint u1 = Hu[(size_t)s1 * 64 + lane];
    uint u2 = Hu[(size_t)s2 * 64 + lane];
    uint u3 = Hu[(size_t)s3 * 64 + lane];
    acc0 += w0 * bflo(u0) + w1 * bflo(u1) + w2 * bflo(u2) + w3 * bflo(u3);
    acc1 += w0 * bfhi(u0) + w1 * bfhi(u1) + w2 * bfhi(u2) + w3 * bfhi(u3);
  }
  for (; i < e; ++i) {
    int s0 = csr_src[i];
    float w0 = csr_w[i];
    uint u0 = Hu[(size_t)s0 * 64 + lane];
    acc0 += w0 * bflo(u0);
    acc1 += w0 * bfhi(u0);
  }
  float2 bb = *(const float2*)(bias + lane * 2);
  acc0 += bb.x; acc1 += bb.y;
  if (outF) {
    float o0 = acc0, o1 = acc1;
    if (actF == 2) { o0 = tanhf(o0); o1 = tanhf(o1); }
    *(float2*)(outF + (size_t)node * 128 + lane * 2) = make_float2(o0, o1);
  }
  if (outB) {
    float o0 = acc0, o1 = acc1;
    if (reluB) { o0 = fmaxf(o0, 0.f); o1 = fmaxf(o1, 0.f); }
    ((uint*)outB)[(size_t)node * 64 + lane] = packbf(o0, o1);
  }
}

// ---------------- aggregation fp32, small C (C=4) ----------------

static __global__ void k_agg_f32(const float* __restrict__ Hm, float* __restrict__ Y,
                                 const int* __restrict__ rowptr, const int* __restrict__ csr_src,
                                 const float* __restrict__ csr_w, const float* __restrict__ dinv,
                                 const float* __restrict__ bias, int N, int C) {
  int idx = blockIdx.x * blockDim.x + threadIdx.x;
  if (idx >= N * C) return;
  int v = idx / C, c = idx - v * C;
  float dv = dinv[v];
  float acc = dv * dv * Hm[(size_t)v * C + c];
  int s = rowptr[v], e = rowptr[v + 1];
  for (int i = s; i < e; ++i) acc += csr_w[i] * Hm[(size_t)csr_src[i] * C + c];
  Y[idx] = acc + bias[c];
}

// ---------------- instance norm (two-stage, coalesced) ----------------

static __global__ __launch_bounds__(256) void k_in_part(const float* __restrict__ X,
                                                        float* __restrict__ acc, int N) {
  int tid = threadIdx.x;
  int c4 = (tid & 31) * 4;
  int rsub = tid >> 5;  // 0..7
  int row0 = blockIdx.x * 512 + rsub;
  int rowEnd = min(blockIdx.x * 512 + 512, N);
  float s0 = 0, s1 = 0, s2 = 0, s3 = 0, q0 = 0, q1 = 0, q2 = 0, q3 = 0;
  for (int r = row0; r < rowEnd; r += 8) {
    float4 v = *(const float4*)(X + (size_t)r * 128 + c4);
    s0 += v.x; s1 += v.y; s2 += v.z; s3 += v.w;
    q0 += v.x * v.x; q1 += v.y * v.y; q2 += v.z * v.z; q3 += v.w * v.w;
  }
  __shared__ float sb[8][132], qb[8][132];
  sb[rsub][c4] = s0; sb[rsub][c4 + 1] = s1; sb[rsub][c4 + 2] = s2; sb[rsub][c4 + 3] = s3;
  qb[rsub][c4] = q0; qb[rsub][c4 + 1] = q1; qb[rsub][c4 + 2] = q2; qb[rsub][c4 + 3] = q3;
  __syncthreads();
  if (tid < 128) {
    float ss = 0, qq = 0;
#pragma unroll
    for (int g = 0; g < 8; ++g) { ss += sb[g][tid]; qq += qb[g][tid]; }
    atomicAdd(&acc[tid], ss);
    atomicAdd(&acc[128 + tid], qq);
  }
}

static __global__ void k_in_fin(const float* __restrict__ acc, float* __restrict__ meanv,
                                float* __restrict__ scalev, int N) {
  int c = threadIdx.x;
  if (c < 128) {
    float m = acc[c] / (float)N;
    float var = acc[128 + c] / (float)N - m * m;
    meanv[c] = m;
    scalev[c] = rsqrtf(var + 1e-5f);
  }
}

// apply + relu + bf16 cast (stride 128)
static __global__ void k_in_apply(const float* __restrict__ X, const float* __restrict__ meanv,
                                  const float* __restrict__ scalev, ushort* __restrict__ outB, int N) {
  int idx = blockIdx.x * blockDim.x + threadIdx.x;
  if (idx >= N * 64) return;
  int c2 = idx & 63;
  float2 x = *(const float2*)(X + (size_t)idx * 2);
  float2 mm = *(const float2*)(meanv + c2 * 2);
  float2 sc = *(const float2*)(scalev + c2 * 2);
  float o0 = fmaxf((x.x - mm.x) * sc.x, 0.f);
  float o1 = fmaxf((x.y - mm.y) * sc.y, 0.f);
  ((uint*)outB)[idx] = packbf(o0, o1);
}

// ---------------- misc elementwise ----------------

static __global__ void k_cast_mesh0(const float* __restrict__ MF, ushort* __restrict__ A16, int N) {
  int idx = blockIdx.x * blockDim.x + threadIdx.x;  // over N*16 (stride 32 bf16)
  if (idx >= N * 16) return;
  int v = idx >> 4, c2 = idx & 15;
  int c = c2 * 2;
  float x0 = 0.f, x1 = 0.f;
  if (c < 8) { x0 = MF[v * 8 + c]; x1 = MF[v * 8 + c + 1]; }
  ((uint*)A16)[idx] = packbf(x0, x1);
}

static __global__ void k_concat16(const float* __restrict__ F, const float* __restrict__ meshL,
                                  ushort* __restrict__ A16, int N) {
  int idx = blockIdx.x * blockDim.x + threadIdx.x;  // over N*80 (stride 160 bf16)
  if (idx >= N * 80) return;
  int v = idx / 80, c2 = idx - v * 80;
  int c = c2 * 2;
  float x0 = 0.f, x1 = 0.f;
  if (c < 4) { x0 = F[v * 4 + c]; x1 = F[v * 4 + c + 1]; }
  else if (c < 132) { float2 m = *(const float2*)(meshL + (size_t)v * 128 + (c - 4)); x0 = m.x; x1 = m.y; }
  ((uint*)A16)[idx] = packbf(x0, x1);
}

static __global__ void k_copy(const float* __restrict__ A, float* __restrict__ B, int n) {
  int i = blockIdx.x * blockDim.x + threadIdx.x;
  if (i < n) B[i] = A[i];
}

static __global__ void k_step_finish(const float* __restrict__ fdot_pre,
                                     const float* __restrict__ Fcur, float* __restrict__ Fnext,
                                     float* __restrict__ out, int N, int T, int t) {
  int idx = blockIdx.x * blockDim.x + threadIdx.x;
  if (idx >= N * 4) return;
  int v = idx >> 2, f = idx & 3;
  float fd = tanhf(fdot_pre[idx]);
  float fn = tanhf(Fcur[idx] + fd * 0.1f);  // DT = 0.1
  Fnext[idx] = fn;
  out[((size_t)v * T + t) * 4 + f] = fn;
  out[(size_t)N * T * 4 + ((size_t)v * T + t) * 4 + f] = fd;
}

// ---------------- host orchestration ----------------

extern "C" void kernel_launch(void* const* d_in, const int* in_sizes, int n_in,
                              void* d_out, int out_size, void* d_ws, size_t ws_size,
                              hipStream_t stream) {
  const float* F0        = (const float*)d_in[0];
  const int*   ei        = (const int*)d_in[1];
  const float* meshfield = (const float*)d_in[2];
  const float* mesh_W0 = (const float*)d_in[4];
  const float* mesh_b0 = (const float*)d_in[5];
  const float* mesh_Wh = (const float*)d_in[6];
  const float* mesh_bh = (const float*)d_in[7];
  const float* mesh_W9 = (const float*)d_in[8];
  const float* mesh_b9 = (const float*)d_in[9];
  const float* diff_W0 = (const float*)d_in[10];
  const float* diff_b0 = (const float*)d_in[11];
  const float* diff_Wh = (const float*)d_in[12];
  const float* diff_bh = (const float*)d_in[13];
  const float* diff_W9 = (const float*)d_in[14];
  const float* diff_b9 = (const float*)d_in[15];

  const int N = in_sizes[0] / 4;          // 30000
  const int E = in_sizes[1] / 2;          // 480000
  const int H = in_sizes[5];              // 128
  const int T = out_size / (N * 4 * 2);   // 4
  const int DEPTH = in_sizes[7] / H;      // 8
  const int Mpad = (N + 127) / 128 * 128; // 30080
  const int DIN_K = 160;                  // 132 padded to 160

  const int* erow = ei;
  const int* ecol = ei + E;

  char* p = (char*)d_ws;
  auto alloc = [&](size_t bytes) { char* r = p; p += (bytes + 255) & ~(size_t)255; return r; };
  float* dinv   = (float*)alloc((size_t)N * 4);
  float* X      = (float*)alloc((size_t)N * H * 4);
  float* meshL  = (float*)alloc((size_t)N * H * 4);
  ushort* A16   = (ushort*)alloc((size_t)Mpad * DIN_K * 2);
  ushort* Msg16 = (ushort*)alloc((size_t)Mpad * H * 2);
  float* msg4   = (float*)alloc((size_t)N * 4 * 4);
  float* fdotp  = (float*)alloc((size_t)N * 4 * 4);
  float* fcur0  = (float*)alloc((size_t)N * 4 * 4);
  float* fcur1  = (float*)alloc((size_t)N * 4 * 4);
  float* statac = (float*)alloc(256 * 4);
  float* meanv  = (float*)alloc(128 * 4);
  float* scalev = (float*)alloc(128 * 4);
  ushort* W0t_m = (ushort*)alloc((size_t)128 * 32 * 2);
  ushort* Wht_m = (ushort*)alloc((size_t)DEPTH * 128 * 128 * 2);
  ushort* W9t_m = (ushort*)alloc((size_t)128 * 128 * 2);
  ushort* W0t_d = (ushort*)alloc((size_t)128 * 160 * 2);
  ushort* Wht_d = (ushort*)alloc((size_t)DEPTH * 128 * 128 * 2);
  float* csr_w  = (float*)alloc((size_t)E * 4);
  int* cnt      = (int*)alloc((size_t)N * 4);
  int* rowptr   = (int*)alloc((size_t)(N + 1) * 4);
  int* fillc    = (int*)alloc((size_t)N * 4);
  int* csr_src  = (int*)alloc((size_t)E * 4);

  // ---- weight prep (bf16, transposed to [n][kpad]) ----
  {
    dim3 g0((128 * 32 + 255) / 256, 1);
    k_wprep<<<g0, 256, 0, stream>>>(mesh_W0, W0t_m, 8, 32, 128);
    dim3 gh((128 * 128 + 255) / 256, DEPTH);
    k_wprep<<<gh, 256, 0, stream>>>(mesh_Wh, Wht_m, 128, 128, 128);
    dim3 g9((128 * 128 + 255) / 256, 1);
    k_wprep<<<g9, 256, 0, stream>>>(mesh_W9, W9t_m, 128, 128, 128);
    dim3 gd((128 * 160 + 255) / 256, 1);
    k_wprep<<<gd, 256, 0, stream>>>(diff_W0, W0t_d, 132, 160, 128);
    k_wprep<<<gh, 256, 0, stream>>>(diff_Wh, Wht_d, 128, 128, 128);
  }

  // ---- graph norm + CSR ----
  hipMemsetAsync(cnt, 0, (size_t)N * 4, stream);
  hipMemsetAsync(fillc, 0, (size_t)N * 4, stream);
  k_count<<<(E + 255) / 256, 256, 0, stream>>>(ecol, cnt, E);
  k_dinv<<<(N + 255) / 256, 256, 0, stream>>>(cnt, dinv, N);
  k_scan<<<1, 1024, 0, stream>>>(cnt, rowptr, N);
  k_fill<<<(E + 255) / 256, 256, 0, stream>>>(erow, ecol, dinv, rowptr, fillc, csr_src, csr_w, E);

  auto gemm = [&](const ushort* A, const ushort* Bt, int K) {
    k_gemm16<<<Mpad / 128, 256, 0, stream>>>(A, Bt, Msg16, N, K);
  };
  auto agg = [&](const float* bias, float* outF, int actF, ushort* outB, int reluB) {
    k_agg16<<<(N + 3) / 4, 256, 0, stream>>>(Msg16, rowptr, csr_src, csr_w, dinv, bias,
                                             outF, actF, outB, reluB, N);
  };
  auto instnorm = [&]() {
    hipMemsetAsync(statac, 0, 256 * 4, stream);
    k_in_part<<<(N + 511) / 512, 256, 0, stream>>>(X, statac, N);
    k_in_fin<<<1, 128, 0, stream>>>(statac, meanv, scalev, N);
    k_in_apply<<<(N * 64 + 255) / 256, 256, 0, stream>>>(X, meanv, scalev, A16, N);
  };

  // ---- mesh descriptor block ----
  k_cast_mesh0<<<(N * 16 + 255) / 256, 256, 0, stream>>>(meshfield, A16, N);
  gemm(A16, W0t_m, 32);
  agg(mesh_b0, X, 0, nullptr, 0);
  instnorm();                                // -> A16 = bf16(relu(norm)), stride 128
  for (int i = 0; i < DEPTH; ++i) {
    gemm(A16, Wht_m + (size_t)i * 128 * 128, 128);
    agg(mesh_bh + (size_t)i * H, nullptr, 0, A16, (i < DEPTH - 1) ? 1 : 0);
  }
  gemm(A16, W9t_m, 128);
  agg(mesh_b9, meshL, 2 /*tanh*/, nullptr, 0);

  // ---- recurrent differentiator ----
  k_copy<<<(N * 4 + 255) / 256, 256, 0, stream>>>(F0, fcur0, N * 4);
  float* fc = fcur0;
  float* fn = fcur1;
  float* out = (float*)d_out;

  for (int t = 0; t < T; ++t) {
    k_concat16<<<(N * 80 + 255) / 256, 256, 0, stream>>>(fc, meshL, A16, N);
    gemm(A16, W0t_d, DIN_K);
    agg(diff_b0, X, 0, nullptr, 0);
    instnorm();
    for (int i = 0; i < DEPTH; ++i) {
      gemm(A16, Wht_d + (size_t)i * 128 * 128, 128);
      agg(diff_bh + (size_t)i * H, nullptr, 0, A16, (i < DEPTH - 1) ? 1 : 0);
    }
    k_gemm_small<<<(N + 255) / 256, 256, 0, stream>>>(A16, diff_W9, msg4, N);
    k_agg_f32<<<(N * 4 + 255) / 256, 256, 0, stream>>>(msg4, fdotp, rowptr, csr_src, csr_w,
                                                       dinv, diff_b9, N, 4);
    k_step_finish<<<(N * 4 + 255) / 256, 256, 0, stream>>>(fdotp, fc, fn, out, N, T, t);
    float* tmp = fc; fc = fn; fn = tmp;
  }
}